// Round 3
// baseline (1375.031 us; speedup 1.0000x reference)
//
#include <hip/hip_runtime.h>
#include <hip/hip_bf16.h>

#define VOCAB_SZ 267735
#define NROWS 512

typedef __attribute__((ext_vector_type(8))) short bf16x8;
typedef __attribute__((ext_vector_type(4))) float f32x4;

typedef const __attribute__((address_space(1))) unsigned int* gas_u32p;
typedef __attribute__((address_space(3))) unsigned int* las_u32p;

// 16B async global->LDS DMA (gfx950). LDS dest must be linear: base + lane*16.
#define GLOAD_LDS16(g, l) \
    __builtin_amdgcn_global_load_lds((gas_u32p)(const void*)(g), (las_u32p)(void*)(l), 16, 0, 0)

enum { MODE_Y = 0, MODE_REDUCE = 1, MODE_WRITE = 2 };

// C[512, N] = A[512, K](bf16) @ B[Npad, K](bf16)^T, double-buffered LDS pipeline:
// prologue stages tile0; each iter issues next tile's 4 global_load_lds, then
// ds_read+MFMA on current, then one __syncthreads (vmcnt(0)+lgkmcnt(0) drain =
// the 2-phase recipe's counted-wait point).  Tile: BM=128, BN=128, BK=32;
// 256 threads = 4 waves (2x2), each wave 64x64 via 4x4 frags of
// v_mfma_f32_16x16x32_bf16.  C/D: col=lane&15, row=(lane>>4)*4+reg (m89/m91).
// B pre-padded to x128 rows so staging never goes OOB; epilogue guards.
template<int MODE>
__global__ __launch_bounds__(256)
void gemm_k(const __hip_bfloat16* __restrict__ A, int lda, int K,
            const __hip_bfloat16* __restrict__ B,
            int Nmat, int Nsplit,
            const float* __restrict__ bias, const float* __restrict__ bias2,
            float* __restrict__ rowsum,
            const float* __restrict__ adj,
            float* __restrict__ outp, int Nstore,
            float* __restrict__ clog,
            __hip_bfloat16* __restrict__ yout, int yld, int ywidth)
{
    const int t = threadIdx.x;
    const int col0 = blockIdx.x * 128;
    const int row0 = blockIdx.y * 128;
    const int wid = t >> 6, lane = t & 63, q = lane >> 4, l16 = lane & 15;
    const int wm = wid >> 1, wn = wid & 1;

    __shared__ __hip_bfloat16 sA[2][128 * 32];   // 8 KB per buffer
    __shared__ __hip_bfloat16 sB[2][128 * 32];
    __shared__ float rs[2][128];

    f32x4 acc[4][4];
    f32x4 zf = {0.f, 0.f, 0.f, 0.f};
#pragma unroll
    for (int i = 0; i < 4; i++)
#pragma unroll
        for (int j = 0; j < 4; j++) acc[i][j] = zf;

    // staging map: 512 chunks of 16B per tile; chunk id -> (row = id>>2, k-half = (id&3)*8)
    const int id0 = t, id1 = 256 + t;
    const __hip_bfloat16* a0 = A + (size_t)(row0 + (id0 >> 2)) * lda + ((id0 & 3) << 3);
    const __hip_bfloat16* a1 = A + (size_t)(row0 + (id1 >> 2)) * lda + ((id1 & 3) << 3);
    const __hip_bfloat16* b0 = B + (size_t)(col0 + (id0 >> 2)) * K + ((id0 & 3) << 3);
    const __hip_bfloat16* b1 = B + (size_t)(col0 + (id1 >> 2)) * K + ((id1 & 3) << 3);
    char* sAb = (char*)sA;
    char* sBb = (char*)sB;

    // prologue: stage tile 0 into buffer 0
    GLOAD_LDS16(a0, sAb + id0 * 16);
    GLOAD_LDS16(a1, sAb + id1 * 16);
    GLOAD_LDS16(b0, sBb + id0 * 16);
    GLOAD_LDS16(b1, sBb + id1 * 16);
    __syncthreads();

    int cur = 0;
    for (int k0 = 32; k0 < K; k0 += 32) {
        const int nxt = cur ^ 1;
        // issue next tile's DMA first (stays in flight across the compute)
        GLOAD_LDS16(a0 + k0, sAb + nxt * 8192 + id0 * 16);
        GLOAD_LDS16(a1 + k0, sAb + nxt * 8192 + id1 * 16);
        GLOAD_LDS16(b0 + k0, sBb + nxt * 8192 + id0 * 16);
        GLOAD_LDS16(b1 + k0, sBb + nxt * 8192 + id1 * 16);

        const bf16x8* sAv = (const bf16x8*)(sAb + cur * 8192);
        const bf16x8* sBv = (const bf16x8*)(sBb + cur * 8192);
        bf16x8 af[4], bfr[4];
#pragma unroll
        for (int i = 0; i < 4; i++) af[i]  = sAv[(wm * 64 + i * 16 + l16) * 4 + q];
#pragma unroll
        for (int j = 0; j < 4; j++) bfr[j] = sBv[(wn * 64 + j * 16 + l16) * 4 + q];
#pragma unroll
        for (int i = 0; i < 4; i++)
#pragma unroll
            for (int j = 0; j < 4; j++)
                acc[i][j] = __builtin_amdgcn_mfma_f32_16x16x32_bf16(af[i], bfr[j], acc[i][j], 0, 0, 0);

        __syncthreads();   // drains prefetch vmcnt + ds_read lgkm, then barrier
        cur = nxt;
    }
    { // tail tile (no prefetch)
        const bf16x8* sAv = (const bf16x8*)(sAb + cur * 8192);
        const bf16x8* sBv = (const bf16x8*)(sBb + cur * 8192);
        bf16x8 af[4], bfr[4];
#pragma unroll
        for (int i = 0; i < 4; i++) af[i]  = sAv[(wm * 64 + i * 16 + l16) * 4 + q];
#pragma unroll
        for (int j = 0; j < 4; j++) bfr[j] = sBv[(wn * 64 + j * 16 + l16) * 4 + q];
#pragma unroll
        for (int i = 0; i < 4; i++)
#pragma unroll
            for (int j = 0; j < 4; j++)
                acc[i][j] = __builtin_amdgcn_mfma_f32_16x16x32_bf16(af[i], bfr[j], acc[i][j], 0, 0, 0);
    }

    int colg[4];
#pragma unroll
    for (int j = 0; j < 4; j++) colg[j] = col0 + wn * 64 + j * 16 + l16;

    if (MODE == MODE_Y) {
#pragma unroll
        for (int i = 0; i < 4; i++) {
            int rbase = row0 + wm * 64 + i * 16 + q * 4;
#pragma unroll
            for (int j = 0; j < 4; j++) {
                if (colg[j] < ywidth) {
#pragma unroll
                    for (int r = 0; r < 4; r++)
                        yout[(size_t)(rbase + r) * yld + colg[j]] = __float2bfloat16(acc[i][j][r]);
                }
            }
        }
    } else if (MODE == MODE_REDUCE) {
        float bv[4]; bool ok[4];
#pragma unroll
        for (int j = 0; j < 4; j++) {
            ok[j] = colg[j] < Nmat;
            bv[j] = colg[j] < Nsplit ? bias[colg[j]] : (ok[j] ? bias2[colg[j] - Nsplit] : 0.f);
        }
#pragma unroll
        for (int i = 0; i < 4; i++) {
            int rbase = row0 + wm * 64 + i * 16 + q * 4;
#pragma unroll
            for (int r = 0; r < 4; r++) {
                int rg = rbase + r;
                float s = 0.f;
#pragma unroll
                for (int j = 0; j < 4; j++) {
                    if (ok[j]) {
                        float v = acc[i][j][r] + bv[j];
                        s += __expf(v);
                        if (clog != nullptr && colg[j] >= Nstore)
                            clog[(colg[j] - Nstore) * NROWS + rg] = v;
                    }
                }
                s += __shfl_xor(s, 1);
                s += __shfl_xor(s, 2);
                s += __shfl_xor(s, 4);
                s += __shfl_xor(s, 8);
                if (l16 == 0) rs[wn][wm * 64 + i * 16 + q * 4 + r] = s;
            }
        }
        __syncthreads();
        if (t < 128) atomicAdd(&rowsum[row0 + t], rs[0][t] + rs[1][t]);
    } else { // MODE_WRITE: out = logit + bias + adj[row]
        float bv[4];
#pragma unroll
        for (int j = 0; j < 4; j++)
            bv[j] = colg[j] < Nsplit ? bias[colg[j]] : (colg[j] < Nmat ? bias2[colg[j] - Nsplit] : 0.f);
#pragma unroll
        for (int i = 0; i < 4; i++) {
            int rbase = row0 + wm * 64 + i * 16 + q * 4;
#pragma unroll
            for (int r = 0; r < 4; r++) {
                int rg = rbase + r;
                float av = adj[rg];
                float* orow = outp + (size_t)rg * VOCAB_SZ;
#pragma unroll
                for (int j = 0; j < 4; j++)
                    if (colg[j] < Nstore)
                        __builtin_nontemporal_store(acc[i][j][r] + bv[j] + av, orow + colg[j]);
            }
        }
    }
}

// ---- one-shot fp32 -> bf16 weight conversion / layout pass -------------------
__device__ inline void cvt8_store(__hip_bfloat16* dst, const float* src)
{
    float4 f0 = ((const float4*)src)[0];
    float4 f1 = ((const float4*)src)[1];
    __hip_bfloat16 h[8] __attribute__((aligned(16)));
    h[0] = __float2bfloat16(f0.x); h[1] = __float2bfloat16(f0.y);
    h[2] = __float2bfloat16(f0.z); h[3] = __float2bfloat16(f0.w);
    h[4] = __float2bfloat16(f1.x); h[5] = __float2bfloat16(f1.y);
    h[6] = __float2bfloat16(f1.z); h[7] = __float2bfloat16(f1.w);
    *((uint4*)dst) = *((uint4*)h);
}
__device__ inline void zero8_store(__hip_bfloat16* dst)
{
    uint4 z = {0u, 0u, 0u, 0u};
    *((uint4*)dst) = z;
}

// Builds (all bf16): hb[512][1024]; pj[1408][1024] = proj0|proj1|proj2|proj3|0;
// wb0[20096][1024] = W0|cw|0; wb1[20096][256] = W1|0; wb2[160000][64] = W2;
// wb3[67840][32] = W3 (K 16->32 zero-padded)|0.  Also zeroes rowsum.
// Chunk = 8 dst elements.
__global__ __launch_bounds__(256)
void conv_k(const float* __restrict__ hidden, const float* __restrict__ cw,
            const float* __restrict__ p0, const float* __restrict__ p1,
            const float* __restrict__ p2, const float* __restrict__ p3,
            const float* __restrict__ W0, const float* __restrict__ W1,
            const float* __restrict__ W2, const float* __restrict__ W3,
            __hip_bfloat16* __restrict__ hb, __hip_bfloat16* __restrict__ pj,
            __hip_bfloat16* __restrict__ wb0, __hip_bfloat16* __restrict__ wb1,
            __hip_bfloat16* __restrict__ wb2, __hip_bfloat16* __restrict__ wb3,
            float* __restrict__ rowsum)
{
    const long gid0 = (long)blockIdx.x * 256 + threadIdx.x;
    if (gid0 < 512) ((float4*)rowsum)[gid0] = make_float4(0.f, 0.f, 0.f, 0.f);
    const long stride = (long)gridDim.x * 256;
    for (long c = gid0; c < 5012480L; c += stride) {
        if (c < 65536L)        { long o = c * 8;              cvt8_store(hb + o, hidden + o); }
        else if (c < 196608L)  { long o = (c - 65536L) * 8;   cvt8_store(pj + o, p0 + o); }
        else if (c < 229376L)  { long o = (c - 196608L) * 8;  cvt8_store(pj + 1048576L + o, p1 + o); }
        else if (c < 237568L)  { long o = (c - 229376L) * 8;  cvt8_store(pj + 1310720L + o, p2 + o); }
        else if (c < 239616L)  { long o = (c - 237568L) * 8;  cvt8_store(pj + 1376256L + o, p3 + o); }
        else if (c < 245760L)  { long o = (c - 239616L) * 8;  zero8_store(pj + 1392640L + o); }
        else if (c < 2805760L) { long o = (c - 245760L) * 8;  cvt8_store(wb0 + o, W0 + o); }
        else if (c < 2806144L) { long o = (c - 2805760L) * 8; cvt8_store(wb0 + 20480000L + o, cw + o); }
        else if (c < 2818048L) { long o = (c - 2806144L) * 8; zero8_store(wb0 + 20483072L + o); }
        else if (c < 3458048L) { long o = (c - 2818048L) * 8; cvt8_store(wb1 + o, W1 + o); }
        else if (c < 3461120L) { long o = (c - 3458048L) * 8; zero8_store(wb1 + 5120000L + o); }
        else if (c < 4741120L) { long o = (c - 3461120L) * 8; cvt8_store(wb2 + o, W2 + o); }
        else {
            long o = (c - 4741120L) * 8;
            long row = o >> 5; int col = (int)(o & 31);
            if (row < 67735L && col < 16) cvt8_store(wb3 + o, W3 + row * 16 + col);
            else                          zero8_store(wb3 + o);
        }
    }
}

__global__ void finalize_k(const float* __restrict__ rowsum, const float* __restrict__ clog,
                           float* __restrict__ adj)
{
    int r = threadIdx.x; // 512 threads, 1 block
    float lse0 = logf(rowsum[r]);
    adj[r]        = -lse0;
    adj[512 + r]  = clog[r]        - lse0 - logf(rowsum[512 + r]);
    adj[1024 + r] = clog[512 + r]  - lse0 - logf(rowsum[1024 + r]);
    adj[1536 + r] = clog[1024 + r] - lse0 - logf(rowsum[1536 + r]);
}

__global__ void loss_k(const float* __restrict__ out, const int* __restrict__ tgt,
                       float* __restrict__ lossp)
{
    __shared__ float sm[512];
    int t = threadIdx.x;
    sm[t] = out[(size_t)t * VOCAB_SZ + tgt[t]];
    __syncthreads();
    for (int s = 256; s > 0; s >>= 1) {
        if (t < s) sm[t] += sm[t + s];
        __syncthreads();
    }
    if (t == 0) lossp[0] = -sm[0] / 512.f;
}

extern "C" void kernel_launch(void* const* d_in, const int* in_sizes, int n_in,
                              void* d_out, int out_size, void* d_ws, size_t ws_size,
                              hipStream_t stream)
{
    const float* hidden = (const float*)d_in[0];
    const int*   target = (const int*)d_in[1];
    const float* cw     = (const float*)d_in[2];
    const float* cb     = (const float*)d_in[3];
    const float* proj[4] = {(const float*)d_in[4], (const float*)d_in[7],
                            (const float*)d_in[10], (const float*)d_in[13]};
    const float* W[4]    = {(const float*)d_in[5], (const float*)d_in[8],
                            (const float*)d_in[11], (const float*)d_in[14]};
    const float* bb[4]   = {(const float*)d_in[6], (const float*)d_in[9],
                            (const float*)d_in[12], (const float*)d_in[15]};
    float* out = (float*)d_out;

    char* ws = (char*)d_ws;
    __hip_bfloat16* hb  = (__hip_bfloat16*)ws;                    // 512x1024
    __hip_bfloat16* y   = (__hip_bfloat16*)(ws + 1048576);        // 512x1408 (y0|y1|y2|y3|0)
    __hip_bfloat16* pj  = (__hip_bfloat16*)(ws + 2490368);        // 1408x1024
    __hip_bfloat16* wb0 = (__hip_bfloat16*)(ws + 5373952);        // 20096x1024
    __hip_bfloat16* wb1 = (__hip_bfloat16*)(ws + 46530560);       // 20096x256
    __hip_bfloat16* wb2 = (__hip_bfloat16*)(ws + 56819712);       // 160000x64
    __hip_bfloat16* wb3 = (__hip_bfloat16*)(ws + 77299712);       // 67840x32
    float* rowsum = (float*)(ws + 81641472);                      // [4][512]
    float* adj    = (float*)(ws + 81649664);                      // [4][512]
    float* clog   = (float*)(ws + 81657856);                      // [3][512]

    conv_k<<<4096, 256, 0, stream>>>(hidden, cw,
        proj[0], proj[1], proj[2], proj[3], W[0], W[1], W[2], W[3],
        hb, pj, wb0, wb1, wb2, wb3, rowsum);

    // y_cat = hidden @ [proj0|proj1|proj2|proj3]^T  (single launch, K=1024)
    gemm_k<MODE_Y><<<dim3(11, 4), 256, 0, stream>>>(hb, 1024, 1024, pj,
        1408, 1408, nullptr, nullptr, nullptr, nullptr, nullptr, 0, nullptr, y, 1408, 1408);

    // pass 1: rowsums (+ cluster pseudo-logit capture on c0)
    gemm_k<MODE_REDUCE><<<dim3(157, 4), 256, 0, stream>>>(y, 1408, 1024, wb0,
        20003, 20000, bb[0], cb, rowsum, nullptr, nullptr, 20000, clog, nullptr, 0, 0);
    gemm_k<MODE_REDUCE><<<dim3(157, 4), 256, 0, stream>>>(y + 1024, 1408, 256, wb1,
        20000, 20000, bb[1], bb[1], rowsum + 512, nullptr, nullptr, 20000, nullptr, nullptr, 0, 0);
    gemm_k<MODE_REDUCE><<<dim3(1250, 4), 256, 0, stream>>>(y + 1280, 1408, 64, wb2,
        160000, 160000, bb[2], bb[2], rowsum + 1024, nullptr, nullptr, 160000, nullptr, nullptr, 0, 0);
    gemm_k<MODE_REDUCE><<<dim3(530, 4), 256, 0, stream>>>(y + 1344, 1408, 32, wb3,
        67735, 67735, bb[3], bb[3], rowsum + 1536, nullptr, nullptr, 67735, nullptr, nullptr, 0, 0);

    finalize_k<<<1, 512, 0, stream>>>(rowsum, clog, adj);

    // pass 2: out = logit + bias + adj[cluster][row]  (single write, no fixup)
    gemm_k<MODE_WRITE><<<dim3(157, 4), 256, 0, stream>>>(y, 1408, 1024, wb0,
        20003, 20000, bb[0], cb, nullptr, adj, out, 20000, nullptr, nullptr, 0, 0);
    gemm_k<MODE_WRITE><<<dim3(157, 4), 256, 0, stream>>>(y + 1024, 1408, 256, wb1,
        20000, 20000, bb[1], bb[1], nullptr, adj + 512, out + 20000, 20000, nullptr, nullptr, 0, 0);
    gemm_k<MODE_WRITE><<<dim3(1250, 4), 256, 0, stream>>>(y + 1280, 1408, 64, wb2,
        160000, 160000, bb[2], bb[2], nullptr, adj + 1024, out + 40000, 160000, nullptr, nullptr, 0, 0);
    gemm_k<MODE_WRITE><<<dim3(530, 4), 256, 0, stream>>>(y + 1344, 1408, 32, wb3,
        67735, 67735, bb[3], bb[3], nullptr, adj + 1536, out + 200000, 67735, nullptr, nullptr, 0, 0);

    loss_k<<<1, 512, 0, stream>>>(out, target, out + (out_size - 1));
}